// Round 2
// baseline (482.428 us; speedup 1.0000x reference)
//
#include <hip/hip_runtime.h>

typedef __attribute__((ext_vector_type(8))) short bf16x8;
typedef __attribute__((ext_vector_type(4))) float f32x4;

#define DEV static __device__ __forceinline__

constexpr int Bn = 4, Seq = 2048, DIN = 1024, E = 1024, H = 16, HD = 64;
constexpr int Mrows = Bn * Seq;   // 8192
constexpr int N3 = 3 * E;         // 3072

DEV unsigned short f2bf(float f) {
  union { float f; unsigned u; } v; v.f = f;
  return (unsigned short)((v.u + 0x7FFFu + ((v.u >> 16) & 1u)) >> 16);
}

typedef const __attribute__((address_space(1))) unsigned int* gas_p;
typedef __attribute__((address_space(3))) unsigned int* las_p;

DEV void gload_lds16(const void* g, void* l) {
  __builtin_amdgcn_global_load_lds((gas_p)g, (las_p)l, 16, 0, 0);
}

DEV float redmax16(float v) {
  v = fmaxf(v, __shfl_xor(v, 1));
  v = fmaxf(v, __shfl_xor(v, 2));
  v = fmaxf(v, __shfl_xor(v, 4));
  v = fmaxf(v, __shfl_xor(v, 8));
  return v;
}
DEV float redsum16(float v) {
  v += __shfl_xor(v, 1);
  v += __shfl_xor(v, 2);
  v += __shfl_xor(v, 4);
  v += __shfl_xor(v, 8);
  return v;
}

// ---------------- cast x (fp32 -> bf16, same layout) ----------------
__global__ void cast_f32_bf16(const float* __restrict__ in,
                              unsigned short* __restrict__ out) {
  size_t i = ((size_t)blockIdx.x * 256 + threadIdx.x) * 8;
  float4 a = *(const float4*)(in + i);
  float4 b = *(const float4*)(in + i + 4);
  union { unsigned short us[8]; bf16x8 v; } r;
  r.us[0] = f2bf(a.x); r.us[1] = f2bf(a.y); r.us[2] = f2bf(a.z); r.us[3] = f2bf(a.w);
  r.us[4] = f2bf(b.x); r.us[5] = f2bf(b.y); r.us[6] = f2bf(b.z); r.us[7] = f2bf(b.w);
  *(bf16x8*)(out + i) = r.v;
}

// ------------- transpose+cast weights: in [K][N] f32 -> out [N][K] bf16 -------------
__global__ void tcast(const float* __restrict__ in, unsigned short* __restrict__ out,
                      int K, int N) {
  __shared__ float tile[64][65];
  int n0 = blockIdx.x * 64, k0 = blockIdx.y * 64;
  int tx = threadIdx.x & 63, ty = threadIdx.x >> 6;
#pragma unroll
  for (int i = 0; i < 64; i += 4)
    tile[ty + i][tx] = in[(size_t)(k0 + ty + i) * N + n0 + tx];
  __syncthreads();
#pragma unroll
  for (int i = 0; i < 64; i += 4)
    out[(size_t)(n0 + ty + i) * K + k0 + tx] = f2bf(tile[tx][ty + i]);
}

// ---------------- GEMM: C[M][N] = A[M][K] * Bt[N][K]^T + bias ----------------
// EPI 0: store bf16. EPI 1: store fp32.
template <int EPI>
__global__ __launch_bounds__(256) void gemm_bt(
    const unsigned short* __restrict__ A, const unsigned short* __restrict__ Bt,
    const float* __restrict__ bias, void* __restrict__ Cout, int N, int K) {
  constexpr int BM = 128, BN = 128, BK = 32;
  __shared__ alignas(16) unsigned short As[BM * BK];
  __shared__ alignas(16) unsigned short Bs[BN * BK];
  const int tid = threadIdx.x;
  const int wave = tid >> 6, lane = tid & 63;
  const int wr = wave >> 1, wc = wave & 1;
  const int llo = lane & 15, lhi = lane >> 4;
  const int bm = blockIdx.y * BM, bn = blockIdx.x * BN;

  f32x4 acc[4][4] = {};

  for (int kt = 0; kt < K; kt += BK) {
#pragma unroll
    for (int i = 0; i < 2; ++i) {
      int chunk = i * 4 + wave;
      int e = (chunk * 64 + lane) * 8;       // bf16 element index in tile
      int row = e >> 5, col = e & 31;
      gload_lds16(A + (size_t)(bm + row) * K + kt + col, (char*)As + chunk * 1024);
      gload_lds16(Bt + (size_t)(bn + row) * K + kt + col, (char*)Bs + chunk * 1024);
    }
    __syncthreads();

    bf16x8 af[4], bfr[4];
#pragma unroll
    for (int mt = 0; mt < 4; ++mt)
      af[mt] = *(const bf16x8*)&As[(wr * 64 + mt * 16 + llo) * BK + lhi * 8];
#pragma unroll
    for (int nt = 0; nt < 4; ++nt)
      bfr[nt] = *(const bf16x8*)&Bs[(wc * 64 + nt * 16 + llo) * BK + lhi * 8];
#pragma unroll
    for (int mt = 0; mt < 4; ++mt)
#pragma unroll
      for (int nt = 0; nt < 4; ++nt)
        acc[mt][nt] =
            __builtin_amdgcn_mfma_f32_16x16x32_bf16(af[mt], bfr[nt], acc[mt][nt], 0, 0, 0);
    __syncthreads();
  }

#pragma unroll
  for (int nt = 0; nt < 4; ++nt) {
    int n = bn + wc * 64 + nt * 16 + llo;
    float bv = bias[n];
#pragma unroll
    for (int mt = 0; mt < 4; ++mt) {
#pragma unroll
      for (int r = 0; r < 4; ++r) {
        int m = bm + wr * 64 + mt * 16 + lhi * 4 + r;
        float v = acc[mt][nt][r] + bv;
        if constexpr (EPI == 0)
          ((unsigned short*)Cout)[(size_t)m * N + n] = f2bf(v);
        else
          ((float*)Cout)[(size_t)m * N + n] = v;
      }
    }
  }
}

// ---------------- flash attention ----------------
// qkv: [B*S][3E] bf16, per (b,s): h*192 + {0:q, 64:k, 128:v}
// O:   [B*S][E]  bf16, (b*S+s)*E + h*64 + d
__global__ __launch_bounds__(256) void attn(const unsigned short* __restrict__ qkv,
                                            unsigned short* __restrict__ O) {
  constexpr int QB = 64, KB = 64;
  __shared__ alignas(16) unsigned short Ks[KB * HD];     // [64][64]
  __shared__ alignas(16) unsigned short VT[HD][72];      // transposed V, padded
  __shared__ alignas(16) unsigned short Ps[4][16][72];   // per-wave P, padded

  const int bh = blockIdx.y, b = bh >> 4, h = bh & 15;
  const int q0 = blockIdx.x * QB;
  const int tid = threadIdx.x, wave = tid >> 6, lane = tid & 63;
  const int llo = lane & 15, lhi = lane >> 4;
  const size_t rs = N3;  // 3072 row stride

  const unsigned short* qbase = qkv + (size_t)(b * Seq) * rs + h * 192;
  const unsigned short* kbase = qbase + 64;
  const unsigned short* vbase = qbase + 128;

  // Q fragments, held in registers for the whole block
  bf16x8 qf[2];
#pragma unroll
  for (int ks = 0; ks < 2; ++ks)
    qf[ks] = *(const bf16x8*)(qbase + (size_t)(q0 + wave * 16 + llo) * rs + ks * 32 + lhi * 8);

  float mrow[4], lrow[4];
  f32x4 oacc[4] = {};
#pragma unroll
  for (int r = 0; r < 4; ++r) { mrow[r] = -1e30f; lrow[r] = 0.f; }

  const int sl = tid >> 2, d0 = (tid & 3) * 16;  // V transpose assignment

  for (int kv0 = 0; kv0 < Seq; kv0 += KB) {
    // stage K (linear, async direct-to-LDS)
#pragma unroll
    for (int i = 0; i < 2; ++i) {
      int chunk = i * 4 + wave;
      int e = (chunk * 64 + lane) * 8;
      int srow = e >> 6, col = e & 63;
      gload_lds16(kbase + (size_t)(kv0 + srow) * rs + col, (char*)Ks + chunk * 1024);
    }
    // stage V transposed (reg round-trip)
    {
      bf16x8 v0 = *(const bf16x8*)(vbase + (size_t)(kv0 + sl) * rs + d0);
      bf16x8 v1 = *(const bf16x8*)(vbase + (size_t)(kv0 + sl) * rs + d0 + 8);
#pragma unroll
      for (int j = 0; j < 8; ++j) {
        VT[d0 + j][sl] = (unsigned short)v0[j];
        VT[d0 + 8 + j][sl] = (unsigned short)v1[j];
      }
    }
    __syncthreads();

    // S = Q K^T  (per wave: 16 q-rows x 64 kv-cols)
    f32x4 sf[4];
#pragma unroll
    for (int nt = 0; nt < 4; ++nt) {
      bf16x8 b0 = *(const bf16x8*)&Ks[(nt * 16 + llo) * 64 + lhi * 8];
      bf16x8 b1 = *(const bf16x8*)&Ks[(nt * 16 + llo) * 64 + 32 + lhi * 8];
      f32x4 t = {};
      t = __builtin_amdgcn_mfma_f32_16x16x32_bf16(qf[0], b0, t, 0, 0, 0);
      t = __builtin_amdgcn_mfma_f32_16x16x32_bf16(qf[1], b1, t, 0, 0, 0);
      sf[nt] = t;
    }
    // scale
#pragma unroll
    for (int nt = 0; nt < 4; ++nt)
#pragma unroll
      for (int r = 0; r < 4; ++r) sf[nt][r] *= 0.125f;

    // online softmax (rows live across 16-lane groups)
    float rfac[4], rsum[4];
#pragma unroll
    for (int r = 0; r < 4; ++r) {
      float mx = fmaxf(fmaxf(sf[0][r], sf[1][r]), fmaxf(sf[2][r], sf[3][r]));
      mx = redmax16(mx);
      float mn = fmaxf(mrow[r], mx);
      rfac[r] = __expf(mrow[r] - mn);
      mrow[r] = mn;
      rsum[r] = 0.f;
    }
#pragma unroll
    for (int nt = 0; nt < 4; ++nt)
#pragma unroll
      for (int r = 0; r < 4; ++r) {
        float p = __expf(sf[nt][r] - mrow[r]);
        sf[nt][r] = p;
        rsum[r] += p;
      }
#pragma unroll
    for (int r = 0; r < 4; ++r) {
      float s = redsum16(rsum[r]);
      lrow[r] = lrow[r] * rfac[r] + s;
    }

    // P -> LDS (bf16), then rescale O accumulator
#pragma unroll
    for (int nt = 0; nt < 4; ++nt)
#pragma unroll
      for (int r = 0; r < 4; ++r)
        Ps[wave][lhi * 4 + r][nt * 16 + llo] = f2bf(sf[nt][r]);
#pragma unroll
    for (int nt = 0; nt < 4; ++nt)
#pragma unroll
      for (int r = 0; r < 4; ++r) oacc[nt][r] *= rfac[r];

    // O += P V
    bf16x8 pa0 = *(const bf16x8*)&Ps[wave][llo][lhi * 8];
    bf16x8 pa1 = *(const bf16x8*)&Ps[wave][llo][32 + lhi * 8];
#pragma unroll
    for (int nt = 0; nt < 4; ++nt) {
      bf16x8 vb0 = *(const bf16x8*)&VT[nt * 16 + llo][lhi * 8];
      bf16x8 vb1 = *(const bf16x8*)&VT[nt * 16 + llo][32 + lhi * 8];
      oacc[nt] = __builtin_amdgcn_mfma_f32_16x16x32_bf16(pa0, vb0, oacc[nt], 0, 0, 0);
      oacc[nt] = __builtin_amdgcn_mfma_f32_16x16x32_bf16(pa1, vb1, oacc[nt], 0, 0, 0);
    }
    __syncthreads();
  }

  // epilogue: O = acc / l
  float inv[4];
#pragma unroll
  for (int r = 0; r < 4; ++r) inv[r] = 1.0f / lrow[r];
  unsigned short* obase = O + (size_t)(b * Seq + q0 + wave * 16) * E + h * 64;
#pragma unroll
  for (int nt = 0; nt < 4; ++nt)
#pragma unroll
    for (int r = 0; r < 4; ++r)
      obase[(size_t)(lhi * 4 + r) * E + nt * 16 + llo] = f2bf(oacc[nt][r] * inv[r]);
}

// ---------------- launch ----------------
extern "C" void kernel_launch(void* const* d_in, const int* in_sizes, int n_in,
                              void* d_out, int out_size, void* d_ws, size_t ws_size,
                              hipStream_t stream) {
  const float* x = (const float*)d_in[0];
  const float* w_qkv = (const float*)d_in[1];
  const float* b_qkv = (const float*)d_in[2];
  const float* w_o = (const float*)d_in[3];
  const float* b_o = (const float*)d_in[4];
  float* out = (float*)d_out;
  char* ws = (char*)d_ws;

  unsigned short* xb = (unsigned short*)(ws + 0);            // 16 MiB
  unsigned short* wqt = (unsigned short*)(ws + 16777216);    // 6 MiB
  unsigned short* wot = (unsigned short*)(ws + 23068672);    // 2 MiB
  unsigned short* qkvb = (unsigned short*)(ws + 25165824);   // 48 MiB
  unsigned short* atO = (unsigned short*)(ws + 75497472);    // 16 MiB

  cast_f32_bf16<<<4096, 256, 0, stream>>>(x, xb);                       // 8192*1024
  tcast<<<dim3(48, 16), 256, 0, stream>>>(w_qkv, wqt, DIN, N3);         // -> [3072][1024]
  tcast<<<dim3(16, 16), 256, 0, stream>>>(w_o, wot, E, E);              // -> [1024][1024]
  gemm_bt<0><<<dim3(N3 / 128, Mrows / 128), 256, 0, stream>>>(xb, wqt, b_qkv, qkvb, N3, DIN);
  attn<<<dim3(Seq / 64, Bn * H), 256, 0, stream>>>(qkvb, atO);
  gemm_bt<1><<<dim3(E / 128, Mrows / 128), 256, 0, stream>>>(atO, wot, b_o, out, E, E);
}

// Round 3
// 423.483 us; speedup vs baseline: 1.1392x; 1.1392x over previous
//
#include <hip/hip_runtime.h>

typedef __attribute__((ext_vector_type(8))) short bf16x8;
typedef __attribute__((ext_vector_type(4))) float f32x4;
typedef __attribute__((ext_vector_type(4))) unsigned short u16x4;

#define DEV static __device__ __forceinline__

constexpr int Bn = 4, Seq = 2048, DIN = 1024, E = 1024, H = 16, HD = 64;
constexpr int Mrows = Bn * Seq;   // 8192
constexpr int N3 = 3 * E;         // 3072

DEV unsigned short f2bf(float f) {
  union { float f; unsigned u; } v; v.f = f;
  return (unsigned short)((v.u + 0x7FFFu + ((v.u >> 16) & 1u)) >> 16);
}

typedef const __attribute__((address_space(1))) unsigned int* gas_p;
typedef __attribute__((address_space(3))) unsigned int* las_p;

DEV void gload_lds16(const void* g, void* l) {
  __builtin_amdgcn_global_load_lds((gas_p)g, (las_p)l, 16, 0, 0);
}

DEV float redmax16(float v) {
  v = fmaxf(v, __shfl_xor(v, 1));
  v = fmaxf(v, __shfl_xor(v, 2));
  v = fmaxf(v, __shfl_xor(v, 4));
  v = fmaxf(v, __shfl_xor(v, 8));
  return v;
}
DEV float redsum16(float v) {
  v += __shfl_xor(v, 1);
  v += __shfl_xor(v, 2);
  v += __shfl_xor(v, 4);
  v += __shfl_xor(v, 8);
  return v;
}

// ---------------- cast x (fp32 -> bf16, same layout) ----------------
__global__ void cast_f32_bf16(const float* __restrict__ in,
                              unsigned short* __restrict__ out) {
  size_t i = ((size_t)blockIdx.x * 256 + threadIdx.x) * 8;
  float4 a = *(const float4*)(in + i);
  float4 b = *(const float4*)(in + i + 4);
  union { unsigned short us[8]; bf16x8 v; } r;
  r.us[0] = f2bf(a.x); r.us[1] = f2bf(a.y); r.us[2] = f2bf(a.z); r.us[3] = f2bf(a.w);
  r.us[4] = f2bf(b.x); r.us[5] = f2bf(b.y); r.us[6] = f2bf(b.z); r.us[7] = f2bf(b.w);
  *(bf16x8*)(out + i) = r.v;
}

// ------------- transpose+cast weights: in [K][N] f32 -> out [N][K] bf16 -------------
__global__ void tcast(const float* __restrict__ in, unsigned short* __restrict__ out,
                      int K, int N) {
  __shared__ float tile[64][65];
  int n0 = blockIdx.x * 64, k0 = blockIdx.y * 64;
  int tx = threadIdx.x & 63, ty = threadIdx.x >> 6;
#pragma unroll
  for (int i = 0; i < 64; i += 4)
    tile[ty + i][tx] = in[(size_t)(k0 + ty + i) * N + n0 + tx];
  __syncthreads();
#pragma unroll
  for (int i = 0; i < 64; i += 4)
    out[(size_t)(n0 + ty + i) * K + k0 + tx] = f2bf(tile[tx][ty + i]);
}

// ---------------- GEMM: C[M][N] = A[M][K] * Bt[N][K]^T + bias ----------------
// EPI 0: store bf16. EPI 1: store fp32.
// VOUT 1: split epilogue — q,k -> Cout as [M][2E] (col h*128+inner),
//         v -> vt as [B*H][64][Seq] (V^T per head), packed ushort4 along s.
template <int EPI, int VOUT>
__global__ __launch_bounds__(256) void gemm_bt(
    const unsigned short* __restrict__ A, const unsigned short* __restrict__ Bt,
    const float* __restrict__ bias, void* __restrict__ Cout,
    unsigned short* __restrict__ vt, int N, int K) {
  constexpr int BM = 128, BN = 128, BK = 32;
  __shared__ alignas(16) unsigned short As[BM * BK];
  __shared__ alignas(16) unsigned short Bs[BN * BK];
  const int tid = threadIdx.x;
  const int wave = tid >> 6, lane = tid & 63;
  const int wr = wave >> 1, wc = wave & 1;
  const int llo = lane & 15, lhi = lane >> 4;
  const int bm = blockIdx.y * BM, bn = blockIdx.x * BN;

  f32x4 acc[4][4] = {};

  for (int kt = 0; kt < K; kt += BK) {
#pragma unroll
    for (int i = 0; i < 2; ++i) {
      int chunk = i * 4 + wave;
      int e = (chunk * 64 + lane) * 8;       // bf16 element index in tile
      int row = e >> 5, col = e & 31;
      gload_lds16(A + (size_t)(bm + row) * K + kt + col, (char*)As + chunk * 1024);
      gload_lds16(Bt + (size_t)(bn + row) * K + kt + col, (char*)Bs + chunk * 1024);
    }
    __syncthreads();

    bf16x8 af[4], bfr[4];
#pragma unroll
    for (int mt = 0; mt < 4; ++mt)
      af[mt] = *(const bf16x8*)&As[(wr * 64 + mt * 16 + llo) * BK + lhi * 8];
#pragma unroll
    for (int nt = 0; nt < 4; ++nt)
      bfr[nt] = *(const bf16x8*)&Bs[(wc * 64 + nt * 16 + llo) * BK + lhi * 8];
#pragma unroll
    for (int mt = 0; mt < 4; ++mt)
#pragma unroll
      for (int nt = 0; nt < 4; ++nt)
        acc[mt][nt] =
            __builtin_amdgcn_mfma_f32_16x16x32_bf16(af[mt], bfr[nt], acc[mt][nt], 0, 0, 0);
    __syncthreads();
  }

#pragma unroll
  for (int nt = 0; nt < 4; ++nt) {
    int n = bn + wc * 64 + nt * 16 + llo;
    float bv = bias[n];
    if constexpr (VOUT == 1) {
      int h = n / 192, inner = n % 192;   // wave-uniform branch per nt (16-spans don't straddle)
      if (inner < 128) {
        int col = h * 128 + inner;
#pragma unroll
        for (int mt = 0; mt < 4; ++mt)
#pragma unroll
          for (int r = 0; r < 4; ++r) {
            int m = bm + wr * 64 + mt * 16 + lhi * 4 + r;
            ((unsigned short*)Cout)[(size_t)m * 2048 + col] = f2bf(acc[mt][nt][r] + bv);
          }
      } else {
        int d = inner - 128;
#pragma unroll
        for (int mt = 0; mt < 4; ++mt) {
          int m = bm + wr * 64 + mt * 16 + lhi * 4;
          int b = m >> 11, s = m & 2047;
          u16x4 pk;
#pragma unroll
          for (int r = 0; r < 4; ++r) pk[r] = f2bf(acc[mt][nt][r] + bv);
          *(u16x4*)&vt[(size_t)((b * 16 + h) * 64 + d) * Seq + s] = pk;
        }
      }
    } else {
#pragma unroll
      for (int mt = 0; mt < 4; ++mt) {
#pragma unroll
        for (int r = 0; r < 4; ++r) {
          int m = bm + wr * 64 + mt * 16 + lhi * 4 + r;
          float v = acc[mt][nt][r] + bv;
          if constexpr (EPI == 0)
            ((unsigned short*)Cout)[(size_t)m * N + n] = f2bf(v);
          else
            ((float*)Cout)[(size_t)m * N + n] = v;
        }
      }
    }
  }
}

// ---------------- flash attention ----------------
// qk: [B*S][2E] bf16, per (b,s): h*128 + {0:q, 64:k}
// vt: [B*H][64][Seq] bf16 (V transposed per head)
// O:  [B*S][E]  bf16, (b*S+s)*E + h*64 + d
__global__ __launch_bounds__(256) void attn(const unsigned short* __restrict__ qk,
                                            const unsigned short* __restrict__ vt,
                                            unsigned short* __restrict__ O) {
  constexpr int KB = 64, NT = Seq / KB;
  // K/V tiles stored with 16B-chunk XOR swizzle: LDS pos (row, c) holds global chunk c ^ (row&7)
  __shared__ alignas(16) unsigned short Ks[2][64 * 64];
  __shared__ alignas(16) unsigned short Vs[2][64 * 64];
  __shared__ alignas(16) unsigned short Ps[4][16][72];

  const int bh = blockIdx.y, b = bh >> 4, h = bh & 15;
  const int q0 = blockIdx.x * 64;
  const int tid = threadIdx.x, wave = tid >> 6, lane = tid & 63;
  const int llo = lane & 15, lhi = lane >> 4;

  const unsigned short* qbase = qk + (size_t)(b * Seq) * 2048 + h * 128;
  const unsigned short* kbase = qbase + 64;
  const unsigned short* vtb = vt + (size_t)bh * 64 * Seq;

  // Q fragments, held in registers for the whole block
  bf16x8 qf[2];
#pragma unroll
  for (int ks = 0; ks < 2; ++ks)
    qf[ks] = *(const bf16x8*)(qbase + (size_t)(q0 + wave * 16 + llo) * 2048 + ks * 32 + lhi * 8);

  const int srow = lane >> 3;                 // 0..7 row-within-chunk
  const int scol = ((lane & 7) ^ srow) * 8;   // pre-swizzled 16B chunk (shorts)

  float mrow[4], lrow[4];
  f32x4 oacc[4] = {};
#pragma unroll
  for (int r = 0; r < 4; ++r) { mrow[r] = -1e30f; lrow[r] = 0.f; }

  // swizzled read offsets (shorts within a row)
  const int c0 = (lhi ^ (llo & 7)) << 3;
  const int c1 = ((lhi ^ (llo & 7)) ^ 4) << 3;

#define STAGE(t, bb)                                                                  \
  {                                                                                   \
    int kv0 = (t) * KB;                                                               \
    _Pragma("unroll") for (int i = 0; i < 2; ++i) {                                   \
      int chunk = i * 4 + wave;                                                       \
      int row = chunk * 8 + srow;                                                     \
      gload_lds16(kbase + (size_t)(kv0 + row) * 2048 + scol,                          \
                  (char*)&Ks[bb][0] + chunk * 1024);                                  \
      gload_lds16(vtb + (size_t)row * Seq + kv0 + scol,                               \
                  (char*)&Vs[bb][0] + chunk * 1024);                                  \
    }                                                                                 \
  }

  STAGE(0, 0);
  asm volatile("s_waitcnt vmcnt(0)" ::: "memory");
  __syncthreads();

  for (int t = 0; t < NT; ++t) {
    const int bb = t & 1;
    if (t + 1 < NT) STAGE(t + 1, bb ^ 1);

    // S = Q K^T  (per wave: 16 q-rows x 64 kv-cols)
    f32x4 sf[4];
#pragma unroll
    for (int nt = 0; nt < 4; ++nt) {
      int rbase = (nt * 16 + llo) * 64;
      bf16x8 b0 = *(const bf16x8*)&Ks[bb][rbase + c0];
      bf16x8 b1 = *(const bf16x8*)&Ks[bb][rbase + c1];
      f32x4 s0 = {};
      s0 = __builtin_amdgcn_mfma_f32_16x16x32_bf16(qf[0], b0, s0, 0, 0, 0);
      s0 = __builtin_amdgcn_mfma_f32_16x16x32_bf16(qf[1], b1, s0, 0, 0, 0);
      sf[nt] = s0;
    }
#pragma unroll
    for (int nt = 0; nt < 4; ++nt)
#pragma unroll
      for (int r = 0; r < 4; ++r) sf[nt][r] *= 0.125f;

    // online softmax (rows live across 16-lane groups)
    float rfac[4], rsum[4];
#pragma unroll
    for (int r = 0; r < 4; ++r) {
      float mx = fmaxf(fmaxf(sf[0][r], sf[1][r]), fmaxf(sf[2][r], sf[3][r]));
      mx = redmax16(mx);
      float mn = fmaxf(mrow[r], mx);
      rfac[r] = __expf(mrow[r] - mn);
      mrow[r] = mn;
      rsum[r] = 0.f;
    }
#pragma unroll
    for (int nt = 0; nt < 4; ++nt)
#pragma unroll
      for (int r = 0; r < 4; ++r) {
        float p = __expf(sf[nt][r] - mrow[r]);
        sf[nt][r] = p;
        rsum[r] += p;
      }
#pragma unroll
    for (int r = 0; r < 4; ++r) {
      float s = redsum16(rsum[r]);
      lrow[r] = lrow[r] * rfac[r] + s;
    }

    // P -> LDS (bf16), rescale O accumulator
#pragma unroll
    for (int nt = 0; nt < 4; ++nt)
#pragma unroll
      for (int r = 0; r < 4; ++r)
        Ps[wave][lhi * 4 + r][nt * 16 + llo] = f2bf(sf[nt][r]);
#pragma unroll
    for (int nt = 0; nt < 4; ++nt)
#pragma unroll
      for (int r = 0; r < 4; ++r) oacc[nt][r] *= rfac[r];

    // O += P V   (V^T rows read with same swizzle)
    bf16x8 pa0 = *(const bf16x8*)&Ps[wave][llo][lhi * 8];
    bf16x8 pa1 = *(const bf16x8*)&Ps[wave][llo][32 + lhi * 8];
#pragma unroll
    for (int nt = 0; nt < 4; ++nt) {
      int rbase = (nt * 16 + llo) * 64;
      bf16x8 vb0 = *(const bf16x8*)&Vs[bb][rbase + c0];
      bf16x8 vb1 = *(const bf16x8*)&Vs[bb][rbase + c1];
      oacc[nt] = __builtin_amdgcn_mfma_f32_16x16x32_bf16(pa0, vb0, oacc[nt], 0, 0, 0);
      oacc[nt] = __builtin_amdgcn_mfma_f32_16x16x32_bf16(pa1, vb1, oacc[nt], 0, 0, 0);
    }

    asm volatile("s_waitcnt vmcnt(0)" ::: "memory");
    __syncthreads();
  }
#undef STAGE

  // epilogue: O = acc / l
  float inv[4];
#pragma unroll
  for (int r = 0; r < 4; ++r) inv[r] = 1.0f / lrow[r];
  unsigned short* obase = O + (size_t)(b * Seq + q0 + wave * 16) * E + h * 64;
#pragma unroll
  for (int nt = 0; nt < 4; ++nt)
#pragma unroll
    for (int r = 0; r < 4; ++r)
      obase[(size_t)(lhi * 4 + r) * E + nt * 16 + llo] = f2bf(oacc[nt][r] * inv[r]);
}

// ---------------- launch ----------------
extern "C" void kernel_launch(void* const* d_in, const int* in_sizes, int n_in,
                              void* d_out, int out_size, void* d_ws, size_t ws_size,
                              hipStream_t stream) {
  const float* x = (const float*)d_in[0];
  const float* w_qkv = (const float*)d_in[1];
  const float* b_qkv = (const float*)d_in[2];
  const float* w_o = (const float*)d_in[3];
  const float* b_o = (const float*)d_in[4];
  float* out = (float*)d_out;
  char* ws = (char*)d_ws;

  unsigned short* xb  = (unsigned short*)(ws + 0);           // 16 MiB
  unsigned short* wqt = (unsigned short*)(ws + 16777216);    // 6 MiB
  unsigned short* wot = (unsigned short*)(ws + 23068672);    // 2 MiB
  unsigned short* qkb = (unsigned short*)(ws + 25165824);    // 32 MiB  [B*S][2E]
  unsigned short* vtb = (unsigned short*)(ws + 58720256);    // 16 MiB  [B*H][64][S]
  unsigned short* atO = (unsigned short*)(ws + 75497472);    // 16 MiB

  cast_f32_bf16<<<4096, 256, 0, stream>>>(x, xb);
  tcast<<<dim3(48, 16), 256, 0, stream>>>(w_qkv, wqt, DIN, N3);
  tcast<<<dim3(16, 16), 256, 0, stream>>>(w_o, wot, E, E);
  gemm_bt<0, 1><<<dim3(N3 / 128, Mrows / 128), 256, 0, stream>>>(xb, wqt, b_qkv, qkb, vtb, N3, DIN);
  attn<<<dim3(Seq / 64, Bn * H), 256, 0, stream>>>(qkb, vtb, atO);
  gemm_bt<1, 0><<<dim3(E / 128, Mrows / 128), 256, 0, stream>>>(atO, wot, b_o, out, nullptr, E, E);
}

// Round 8
// 330.579 us; speedup vs baseline: 1.4593x; 1.2810x over previous
//
#include <hip/hip_runtime.h>

typedef __attribute__((ext_vector_type(8))) short bf16x8;
typedef __attribute__((ext_vector_type(4))) float f32x4;
typedef __attribute__((ext_vector_type(16))) float f32x16;
typedef __attribute__((ext_vector_type(4))) unsigned short u16x4;

#define DEV static __device__ __forceinline__

constexpr int Bn = 4, Seq = 2048, DIN = 1024, E = 1024, H = 16, HD = 64;
constexpr int Mrows = Bn * Seq;   // 8192
constexpr int N3 = 3 * E;         // 3072

DEV unsigned short f2bf(float f) {
  union { float f; unsigned u; } v; v.f = f;
  return (unsigned short)((v.u + 0x7FFFu + ((v.u >> 16) & 1u)) >> 16);
}

typedef const __attribute__((address_space(1))) unsigned int* gas_p;
typedef __attribute__((address_space(3))) unsigned int* las_p;

DEV void gload_lds16(const void* g, void* l) {
  __builtin_amdgcn_global_load_lds((gas_p)g, (las_p)l, 16, 0, 0);
}

DEV unsigned cvtpk_bf16(float lo, float hi) {
  unsigned r;
  asm("v_cvt_pk_bf16_f32 %0, %1, %2" : "=v"(r) : "v"(lo), "v"(hi));
  return r;
}
DEV float exp2fast(float x) {
  float r;
  asm("v_exp_f32 %0, %1" : "=v"(r) : "v"(x));
  return r;
}
DEV unsigned shx32(unsigned v) { return (unsigned)__shfl_xor((int)v, 32, 64); }
DEV bf16x8 pack4(unsigned w0, unsigned w1, unsigned w2, unsigned w3) {
  union { unsigned u[4]; bf16x8 b; } cv;
  cv.u[0] = w0; cv.u[1] = w1; cv.u[2] = w2; cv.u[3] = w3;
  return cv.b;
}

// ---------------- cast x (fp32 -> bf16, same layout) ----------------
__global__ void cast_f32_bf16(const float* __restrict__ in,
                              unsigned short* __restrict__ out) {
  size_t i = ((size_t)blockIdx.x * 256 + threadIdx.x) * 8;
  float4 a = *(const float4*)(in + i);
  float4 b = *(const float4*)(in + i + 4);
  union { unsigned short us[8]; bf16x8 v; } r;
  r.us[0] = f2bf(a.x); r.us[1] = f2bf(a.y); r.us[2] = f2bf(a.z); r.us[3] = f2bf(a.w);
  r.us[4] = f2bf(b.x); r.us[5] = f2bf(b.y); r.us[6] = f2bf(b.z); r.us[7] = f2bf(b.w);
  *(bf16x8*)(out + i) = r.v;
}

// ------------- transpose+cast weights: in [K][N] f32 -> out [N][K] bf16 -------------
__global__ void tcast(const float* __restrict__ in, unsigned short* __restrict__ out,
                      int K, int N) {
  __shared__ float tile[64][65];
  int n0 = blockIdx.x * 64, k0 = blockIdx.y * 64;
  int tx = threadIdx.x & 63, ty = threadIdx.x >> 6;
#pragma unroll
  for (int i = 0; i < 64; i += 4)
    tile[ty + i][tx] = in[(size_t)(k0 + ty + i) * N + n0 + tx];
  __syncthreads();
#pragma unroll
  for (int i = 0; i < 64; i += 4)
    out[(size_t)(n0 + ty + i) * K + k0 + tx] = f2bf(tile[tx][ty + i]);
}

// ---------------- GEMM: C[M][N] = A[M][K] * Bt[N][K]^T + bias ----------------
template <int EPI, int VOUT>
__global__ __launch_bounds__(256) void gemm_bt(
    const unsigned short* __restrict__ A, const unsigned short* __restrict__ Bt,
    const float* __restrict__ bias, void* __restrict__ Cout,
    unsigned short* __restrict__ vt, int N, int K) {
  constexpr int BM = 128, BN = 128, BK = 32;
  __shared__ alignas(16) unsigned short As[BM * BK];
  __shared__ alignas(16) unsigned short Bs[BN * BK];
  const int tid = threadIdx.x;
  const int wave = tid >> 6, lane = tid & 63;
  const int wr = wave >> 1, wc = wave & 1;
  const int llo = lane & 15, lhi = lane >> 4;
  const int bm = blockIdx.y * BM, bn = blockIdx.x * BN;

  f32x4 acc[4][4] = {};

  for (int kt = 0; kt < K; kt += BK) {
#pragma unroll
    for (int i = 0; i < 2; ++i) {
      int chunk = i * 4 + wave;
      int e = (chunk * 64 + lane) * 8;
      int row = e >> 5, col = e & 31;
      gload_lds16(A + (size_t)(bm + row) * K + kt + col, (char*)As + chunk * 1024);
      gload_lds16(Bt + (size_t)(bn + row) * K + kt + col, (char*)Bs + chunk * 1024);
    }
    __syncthreads();

    bf16x8 af[4], bfr[4];
#pragma unroll
    for (int mt = 0; mt < 4; ++mt)
      af[mt] = *(const bf16x8*)&As[(wr * 64 + mt * 16 + llo) * BK + lhi * 8];
#pragma unroll
    for (int nt = 0; nt < 4; ++nt)
      bfr[nt] = *(const bf16x8*)&Bs[(wc * 64 + nt * 16 + llo) * BK + lhi * 8];
#pragma unroll
    for (int mt = 0; mt < 4; ++mt)
#pragma unroll
      for (int nt = 0; nt < 4; ++nt)
        acc[mt][nt] =
            __builtin_amdgcn_mfma_f32_16x16x32_bf16(af[mt], bfr[nt], acc[mt][nt], 0, 0, 0);
    __syncthreads();
  }

#pragma unroll
  for (int nt = 0; nt < 4; ++nt) {
    int n = bn + wc * 64 + nt * 16 + llo;
    float bv = bias[n];
    if constexpr (VOUT == 1) {
      int h = n / 192, inner = n % 192;
      if (inner < 128) {
        int col = h * 128 + inner;
#pragma unroll
        for (int mt = 0; mt < 4; ++mt)
#pragma unroll
          for (int r = 0; r < 4; ++r) {
            int m = bm + wr * 64 + mt * 16 + lhi * 4 + r;
            ((unsigned short*)Cout)[(size_t)m * 2048 + col] = f2bf(acc[mt][nt][r] + bv);
          }
      } else {
        int d = inner - 128;
#pragma unroll
        for (int mt = 0; mt < 4; ++mt) {
          int m = bm + wr * 64 + mt * 16 + lhi * 4;
          int b = m >> 11, s = m & 2047;
          u16x4 pk;
#pragma unroll
          for (int r = 0; r < 4; ++r) pk[r] = f2bf(acc[mt][nt][r] + bv);
          *(u16x4*)&vt[(size_t)((b * 16 + h) * 64 + d) * Seq + s] = pk;
        }
      }
    } else {
#pragma unroll
      for (int mt = 0; mt < 4; ++mt) {
#pragma unroll
        for (int r = 0; r < 4; ++r) {
          int m = bm + wr * 64 + mt * 16 + lhi * 4 + r;
          float v = acc[mt][nt][r] + bv;
          if constexpr (EPI == 0)
            ((unsigned short*)Cout)[(size_t)m * N + n] = f2bf(v);
          else
            ((float*)Cout)[(size_t)m * N + n] = v;
        }
      }
    }
  }
}

// ---------------- flash attention (swapped-QK^T, 32x32 MFMA, in-register softmax) ----
// qk: [B*S][2E] bf16, per (b,s): h*128 + {0:q, 64:k}
// vt: [B*H][64][Seq] bf16 (V^T per head)
// O:  [B*S][E]  bf16
// Half-exchange done via __shfl_xor(.,32) + cndmask (direction-proof).
__global__ __launch_bounds__(256) void attn(const unsigned short* __restrict__ qk,
                                            const unsigned short* __restrict__ vt,
                                            unsigned short* __restrict__ O) {
  constexpr int KB = 64, NT = Seq / KB;
  constexpr float SCL = 0.18033688011112042f;  // 0.125 * log2(e)
  __shared__ alignas(16) unsigned short Ks[2][64 * 64];  // [k][d], 16B-chunk XOR swizzled
  __shared__ alignas(16) unsigned short Vs[2][64 * 64];  // [d][k], same swizzle
  __shared__ float rbc[4][32];                           // per-wave broadcast line

  const int bh = blockIdx.y, b = bh >> 4, h = bh & 15;
  const int q0 = blockIdx.x * 128;
  const int tid = threadIdx.x, wq = tid >> 6, lane = tid & 63;
  const int lq = lane & 31, hi = lane >> 5;

  const unsigned short* qbase = qk + (size_t)(b * Seq) * 2048 + h * 128;
  const unsigned short* kbase = qbase + 64;
  const unsigned short* vtb = vt + (size_t)bh * 64 * Seq;

  // Q B-fragments: lane holds q-row lq, d = ds*16 + hi*8 + 0..7
  bf16x8 qf[4];
  {
    const unsigned short* qrow = qbase + (size_t)(q0 + wq * 32 + lq) * 2048 + hi * 8;
#pragma unroll
    for (int ds = 0; ds < 4; ++ds) qf[ds] = *(const bf16x8*)(qrow + ds * 16);
  }

  float m = -1e30f, l = 0.f;
  f32x16 oacc[2] = {};

  const int srow = lane >> 3;
  const int scol = ((lane & 7) ^ srow) * 8;  // pre-swizzled source chunk

#define STAGE(t, bb)                                                         \
  {                                                                          \
    int kv0 = (t) * KB;                                                      \
    _Pragma("unroll") for (int i = 0; i < 2; ++i) {                          \
      int chunk = i * 4 + wq;                                                \
      int row = chunk * 8 + srow;                                            \
      gload_lds16(kbase + (size_t)(kv0 + row) * 2048 + scol,                 \
                  (char*)&Ks[bb][0] + chunk * 1024);                         \
      gload_lds16(vtb + (size_t)row * Seq + kv0 + scol,                      \
                  (char*)&Vs[bb][0] + chunk * 1024);                         \
    }                                                                        \
  }

// Build A-fragment words from 8 consecutive P regs (k-rows base..base+7 of a 32-row half).
// own pairs: a0=(rows b+0,b+1), a1=(b+2,b+3), b0=(b+4,b+5), b1=(b+6,b+7)
// frag word j01 = hi ? partner(b0) : a0 ; j45 = hi ? b0 : partner(a0); likewise j23/j67.
#define MKFRAG(dst, s, base)                                                  \
  {                                                                           \
    unsigned a0 = cvtpk_bf16(s[base + 0], s[base + 1]);                       \
    unsigned a1 = cvtpk_bf16(s[base + 2], s[base + 3]);                       \
    unsigned b0 = cvtpk_bf16(s[base + 4], s[base + 5]);                       \
    unsigned b1 = cvtpk_bf16(s[base + 6], s[base + 7]);                       \
    unsigned oa0 = shx32(a0), oa1 = shx32(a1), ob0 = shx32(b0), ob1 = shx32(b1); \
    dst = pack4(hi ? ob0 : a0, hi ? ob1 : a1, hi ? b0 : oa0, hi ? b1 : oa1);  \
  }

  STAGE(0, 0);
  asm volatile("s_waitcnt vmcnt(0)" ::: "memory");
  __syncthreads();

  for (int t = 0; t < NT; ++t) {
    const int bb = t & 1;
    if (t + 1 < NT) STAGE(t + 1, bb ^ 1);

    // ---- S^T = K Q^T : sa0 = k-rows 0..31, sa1 = k-rows 32..63 ----
    f32x16 sa0 = {}, sa1 = {};
#pragma unroll
    for (int ds = 0; ds < 4; ++ds) {
      const int ch = 2 * ds + hi;
      bf16x8 k0 = *(const bf16x8*)&Ks[bb][lq * 64 + ((ch ^ (lq & 7)) << 3)];
      bf16x8 k1 = *(const bf16x8*)&Ks[bb][(32 + lq) * 64 + ((ch ^ (lq & 7)) << 3)];
      sa0 = __builtin_amdgcn_mfma_f32_32x32x16_bf16(k0, qf[ds], sa0, 0, 0, 0);
      sa1 = __builtin_amdgcn_mfma_f32_32x32x16_bf16(k1, qf[ds], sa1, 0, 0, 0);
    }

    // ---- online softmax, fully in-register (q = lq; k split across lane pair) ----
    float tmx[16];
#pragma unroll
    for (int i = 0; i < 16; ++i) tmx[i] = fmaxf(sa0[i], sa1[i]);
#pragma unroll
    for (int st = 8; st > 0; st >>= 1)
#pragma unroll
      for (int i = 0; i < st; ++i) tmx[i] = fmaxf(tmx[i], tmx[i + st]);
    float pmax = tmx[0];
    pmax = fmaxf(pmax, __shfl_xor(pmax, 32, 64));

    float mnew = fmaxf(m, pmax);
    float rfac = exp2fast((m - mnew) * SCL);
    m = mnew;
    float nmc = -m * SCL;

#pragma unroll
    for (int i = 0; i < 16; ++i) sa0[i] = exp2fast(fmaf(sa0[i], SCL, nmc));
#pragma unroll
    for (int i = 0; i < 16; ++i) sa1[i] = exp2fast(fmaf(sa1[i], SCL, nmc));

    float ts[16];
#pragma unroll
    for (int i = 0; i < 16; ++i) ts[i] = sa0[i] + sa1[i];
#pragma unroll
    for (int st = 8; st > 0; st >>= 1)
#pragma unroll
      for (int i = 0; i < st; ++i) ts[i] += ts[i + st];
    float psum = ts[0];
    psum += __shfl_xor(psum, 32, 64);
    l = l * rfac + psum;

    // ---- P -> bf16 A-fragments (cvt_pk + shfl_xor exchange; no LDS) ----
    bf16x8 pav[4];
    MKFRAG(pav[0], sa0, 0);
    MKFRAG(pav[1], sa0, 8);
    MKFRAG(pav[2], sa1, 0);
    MKFRAG(pav[3], sa1, 8);

    // ---- per-q rescale of O (q lives in reg dim: q = (i&3)+8*(i>>2)+4*hi) ----
    if (hi == 0) rbc[wq][lq] = rfac;
    f32x4 rf[4];
#pragma unroll
    for (int g = 0; g < 4; ++g) rf[g] = *(const f32x4*)&rbc[wq][g * 8 + hi * 4];
#pragma unroll
    for (int i = 0; i < 16; ++i) {
      float r = rf[i >> 2][i & 3];
      oacc[0][i] *= r;
      oacc[1][i] *= r;
    }

    // ---- O += P V ----
#pragma unroll
    for (int ks = 0; ks < 4; ++ks) {
      const int ch = 2 * ks + hi;
      bf16x8 v0 = *(const bf16x8*)&Vs[bb][lq * 64 + ((ch ^ (lq & 7)) << 3)];
      bf16x8 v1 = *(const bf16x8*)&Vs[bb][(32 + lq) * 64 + ((ch ^ (lq & 7)) << 3)];
      oacc[0] = __builtin_amdgcn_mfma_f32_32x32x16_bf16(pav[ks], v0, oacc[0], 0, 0, 0);
      oacc[1] = __builtin_amdgcn_mfma_f32_32x32x16_bf16(pav[ks], v1, oacc[1], 0, 0, 0);
    }

    asm volatile("s_waitcnt vmcnt(0)" ::: "memory");
    __syncthreads();
  }
#undef STAGE
#undef MKFRAG

  // ---- epilogue: O = acc / l ----
  if (hi == 0) rbc[wq][lq] = 1.0f / l;
  f32x4 lf[4];
#pragma unroll
  for (int g = 0; g < 4; ++g) lf[g] = *(const f32x4*)&rbc[wq][g * 8 + hi * 4];
  unsigned short* ob = O + (size_t)(b * Seq + q0 + wq * 32) * E + h * 64 + lq;
#pragma unroll
  for (int db = 0; db < 2; ++db)
#pragma unroll
    for (int i = 0; i < 16; ++i) {
      int ql = (i & 3) + 8 * (i >> 2) + 4 * hi;
      ob[(size_t)ql * E + db * 32] = f2bf(oacc[db][i] * lf[i >> 2][i & 3]);
    }
}

// ---------------- launch ----------------
extern "C" void kernel_launch(void* const* d_in, const int* in_sizes, int n_in,
                              void* d_out, int out_size, void* d_ws, size_t ws_size,
                              hipStream_t stream) {
  const float* x = (const float*)d_in[0];
  const float* w_qkv = (const float*)d_in[1];
  const float* b_qkv = (const float*)d_in[2];
  const float* w_o = (const float*)d_in[3];
  const float* b_o = (const float*)d_in[4];
  float* out = (float*)d_out;
  char* ws = (char*)d_ws;

  unsigned short* xb  = (unsigned short*)(ws + 0);           // 16 MiB
  unsigned short* wqt = (unsigned short*)(ws + 16777216);    // 6 MiB
  unsigned short* wot = (unsigned short*)(ws + 23068672);    // 2 MiB
  unsigned short* qkb = (unsigned short*)(ws + 25165824);    // 32 MiB  [B*S][2E]
  unsigned short* vtb = (unsigned short*)(ws + 58720256);    // 16 MiB  [B*H][64][S]
  unsigned short* atO = (unsigned short*)(ws + 75497472);    // 16 MiB

  cast_f32_bf16<<<4096, 256, 0, stream>>>(x, xb);
  tcast<<<dim3(48, 16), 256, 0, stream>>>(w_qkv, wqt, DIN, N3);
  tcast<<<dim3(16, 16), 256, 0, stream>>>(w_o, wot, E, E);
  gemm_bt<0, 1><<<dim3(N3 / 128, Mrows / 128), 256, 0, stream>>>(xb, wqt, b_qkv, qkb, vtb, N3, DIN);
  attn<<<dim3(Seq / 128, Bn * H), 256, 0, stream>>>(qkb, vtb, atO);
  gemm_bt<1, 0><<<dim3(E / 128, Mrows / 128), 256, 0, stream>>>(atO, wot, b_o, out, nullptr, E, E);
}

// Round 9
// 327.707 us; speedup vs baseline: 1.4721x; 1.0088x over previous
//
#include <hip/hip_runtime.h>

typedef __attribute__((ext_vector_type(8))) short bf16x8;
typedef __attribute__((ext_vector_type(4))) float f32x4;
typedef __attribute__((ext_vector_type(16))) float f32x16;
typedef __attribute__((ext_vector_type(4))) unsigned short u16x4;

#define DEV static __device__ __forceinline__

constexpr int Bn = 4, Seq = 2048, DIN = 1024, E = 1024, H = 16, HD = 64;
constexpr int Mrows = Bn * Seq;   // 8192
constexpr int N3 = 3 * E;         // 3072

DEV unsigned short f2bf(float f) {
  union { float f; unsigned u; } v; v.f = f;
  return (unsigned short)((v.u + 0x7FFFu + ((v.u >> 16) & 1u)) >> 16);
}

typedef const __attribute__((address_space(1))) unsigned int* gas_p;
typedef __attribute__((address_space(3))) unsigned int* las_p;

DEV void gload_lds16(const void* g, void* l) {
  __builtin_amdgcn_global_load_lds((gas_p)g, (las_p)l, 16, 0, 0);
}

DEV unsigned cvtpk_bf16(float lo, float hi) {
  unsigned r;
  asm("v_cvt_pk_bf16_f32 %0, %1, %2" : "=v"(r) : "v"(lo), "v"(hi));
  return r;
}
DEV float exp2fast(float x) {
  float r;
  asm("v_exp_f32 %0, %1" : "=v"(r) : "v"(x));
  return r;
}
DEV unsigned shx32(unsigned v) { return (unsigned)__shfl_xor((int)v, 32, 64); }
DEV bf16x8 pack4(unsigned w0, unsigned w1, unsigned w2, unsigned w3) {
  union { unsigned u[4]; bf16x8 b; } cv;
  cv.u[0] = w0; cv.u[1] = w1; cv.u[2] = w2; cv.u[3] = w3;
  return cv.b;
}

// ---------------- cast x (fp32 -> bf16, same layout) ----------------
__global__ void cast_f32_bf16(const float* __restrict__ in,
                              unsigned short* __restrict__ out) {
  size_t i = ((size_t)blockIdx.x * 256 + threadIdx.x) * 8;
  float4 a = *(const float4*)(in + i);
  float4 b = *(const float4*)(in + i + 4);
  union { unsigned short us[8]; bf16x8 v; } r;
  r.us[0] = f2bf(a.x); r.us[1] = f2bf(a.y); r.us[2] = f2bf(a.z); r.us[3] = f2bf(a.w);
  r.us[4] = f2bf(b.x); r.us[5] = f2bf(b.y); r.us[6] = f2bf(b.z); r.us[7] = f2bf(b.w);
  *(bf16x8*)(out + i) = r.v;
}

// ------------- transpose+cast weights: in [K][N] f32 -> out [N][K] bf16 -------------
__global__ void tcast(const float* __restrict__ in, unsigned short* __restrict__ out,
                      int K, int N) {
  __shared__ float tile[64][65];
  int n0 = blockIdx.x * 64, k0 = blockIdx.y * 64;
  int tx = threadIdx.x & 63, ty = threadIdx.x >> 6;
#pragma unroll
  for (int i = 0; i < 64; i += 4)
    tile[ty + i][tx] = in[(size_t)(k0 + ty + i) * N + n0 + tx];
  __syncthreads();
#pragma unroll
  for (int i = 0; i < 64; i += 4)
    out[(size_t)(n0 + ty + i) * K + k0 + tx] = f2bf(tile[tx][ty + i]);
}

// ---------------- GEMM: C[M][N] = A[M][K] * Bt[N][K]^T + bias ----------------
// 1D grid, XCD-chunked L2 blocking: xcd = bid%8 owns 8 consecutive m-blocks;
// within chunk m varies fastest (8 m-blocks share each B-panel in L2, A-chunk
// 2 MiB stays resident). M is fixed at 8192 (64 m-blocks, 8 per XCD).
template <int EPI, int VOUT>
__global__ __launch_bounds__(256) void gemm_bt(
    const unsigned short* __restrict__ A, const unsigned short* __restrict__ Bt,
    const float* __restrict__ bias, void* __restrict__ Cout,
    unsigned short* __restrict__ vt, int N, int K) {
  constexpr int BM = 128, BN = 128, BK = 32;
  __shared__ alignas(16) unsigned short As[BM * BK];
  __shared__ alignas(16) unsigned short Bs[BN * BK];
  const int tid = threadIdx.x;
  const int wave = tid >> 6, lane = tid & 63;
  const int wr = wave >> 1, wc = wave & 1;
  const int llo = lane & 15, lhi = lane >> 4;
  const int j = blockIdx.x >> 3, xcd = blockIdx.x & 7;
  const int mb = xcd * 8 + (j & 7), nb = j >> 3;
  const int bm = mb << 7, bn = nb << 7;

  f32x4 acc[4][4] = {};

  for (int kt = 0; kt < K; kt += BK) {
#pragma unroll
    for (int i = 0; i < 2; ++i) {
      int chunk = i * 4 + wave;
      int e = (chunk * 64 + lane) * 8;
      int row = e >> 5, col = e & 31;
      gload_lds16(A + (size_t)(bm + row) * K + kt + col, (char*)As + chunk * 1024);
      gload_lds16(Bt + (size_t)(bn + row) * K + kt + col, (char*)Bs + chunk * 1024);
    }
    __syncthreads();

    bf16x8 af[4], bfr[4];
#pragma unroll
    for (int mt = 0; mt < 4; ++mt)
      af[mt] = *(const bf16x8*)&As[(wr * 64 + mt * 16 + llo) * BK + lhi * 8];
#pragma unroll
    for (int nt = 0; nt < 4; ++nt)
      bfr[nt] = *(const bf16x8*)&Bs[(wc * 64 + nt * 16 + llo) * BK + lhi * 8];
#pragma unroll
    for (int mt = 0; mt < 4; ++mt)
#pragma unroll
      for (int nt = 0; nt < 4; ++nt)
        acc[mt][nt] =
            __builtin_amdgcn_mfma_f32_16x16x32_bf16(af[mt], bfr[nt], acc[mt][nt], 0, 0, 0);
    __syncthreads();
  }

#pragma unroll
  for (int nt = 0; nt < 4; ++nt) {
    int n = bn + wc * 64 + nt * 16 + llo;
    float bv = bias[n];
    if constexpr (VOUT == 1) {
      int h = n / 192, inner = n % 192;
      if (inner < 128) {
        int col = h * 128 + inner;
#pragma unroll
        for (int mt = 0; mt < 4; ++mt)
#pragma unroll
          for (int r = 0; r < 4; ++r) {
            int m = bm + wr * 64 + mt * 16 + lhi * 4 + r;
            ((unsigned short*)Cout)[(size_t)m * 2048 + col] = f2bf(acc[mt][nt][r] + bv);
          }
      } else {
        int d = inner - 128;
#pragma unroll
        for (int mt = 0; mt < 4; ++mt) {
          int m = bm + wr * 64 + mt * 16 + lhi * 4;
          int b = m >> 11, s = m & 2047;
          u16x4 pk;
#pragma unroll
          for (int r = 0; r < 4; ++r) pk[r] = f2bf(acc[mt][nt][r] + bv);
          *(u16x4*)&vt[(size_t)((b * 16 + h) * 64 + d) * Seq + s] = pk;
        }
      }
    } else {
#pragma unroll
      for (int mt = 0; mt < 4; ++mt) {
#pragma unroll
        for (int r = 0; r < 4; ++r) {
          int m = bm + wr * 64 + mt * 16 + lhi * 4 + r;
          float v = acc[mt][nt][r] + bv;
          if constexpr (EPI == 0)
            ((unsigned short*)Cout)[(size_t)m * N + n] = f2bf(v);
          else
            ((float*)Cout)[(size_t)m * N + n] = v;
        }
      }
    }
  }
}

// ---------------- flash attention (swapped-QK^T, 32x32 MFMA, in-register softmax) ----
// qk: [B*S][2E] bf16, per (b,s): h*128 + {0:q, 64:k}
// vt: [B*H][64][Seq] bf16 (V^T per head)
// O:  [B*S][E]  bf16
// Half-exchange via __shfl_xor(.,32) (direction-proof). T13 defer-max rescale.
__global__ __launch_bounds__(256) void attn(const unsigned short* __restrict__ qk,
                                            const unsigned short* __restrict__ vt,
                                            unsigned short* __restrict__ O) {
  constexpr int KB = 64, NT = Seq / KB;
  constexpr float SCL = 0.18033688011112042f;  // 0.125 * log2(e)
  constexpr float THR = 32.0f;                 // raw-logit defer threshold (P <= 2^5.8)
  __shared__ alignas(16) unsigned short Ks[2][64 * 64];  // [k][d], 16B-chunk XOR swizzled
  __shared__ alignas(16) unsigned short Vs[2][64 * 64];  // [d][k], same swizzle
  __shared__ float rbc[4][32];                           // per-wave broadcast line

  const int bh = blockIdx.y, b = bh >> 4, h = bh & 15;
  const int q0 = blockIdx.x * 128;
  const int tid = threadIdx.x, wq = tid >> 6, lane = tid & 63;
  const int lq = lane & 31, hi = lane >> 5;

  const unsigned short* qbase = qk + (size_t)(b * Seq) * 2048 + h * 128;
  const unsigned short* kbase = qbase + 64;
  const unsigned short* vtb = vt + (size_t)bh * 64 * Seq;

  // Q B-fragments: lane holds q-row lq, d = ds*16 + hi*8 + 0..7
  bf16x8 qf[4];
  {
    const unsigned short* qrow = qbase + (size_t)(q0 + wq * 32 + lq) * 2048 + hi * 8;
#pragma unroll
    for (int ds = 0; ds < 4; ++ds) qf[ds] = *(const bf16x8*)(qrow + ds * 16);
  }

  float m = -1e30f, l = 0.f;
  f32x16 oacc[2] = {};

  const int srow = lane >> 3;
  const int scol = ((lane & 7) ^ srow) * 8;  // pre-swizzled source chunk

#define STAGE(t, bb)                                                         \
  {                                                                          \
    int kv0 = (t) * KB;                                                      \
    _Pragma("unroll") for (int i = 0; i < 2; ++i) {                          \
      int chunk = i * 4 + wq;                                                \
      int row = chunk * 8 + srow;                                            \
      gload_lds16(kbase + (size_t)(kv0 + row) * 2048 + scol,                 \
                  (char*)&Ks[bb][0] + chunk * 1024);                         \
      gload_lds16(vtb + (size_t)row * Seq + kv0 + scol,                      \
                  (char*)&Vs[bb][0] + chunk * 1024);                         \
    }                                                                        \
  }

// Build A-fragment words from 8 consecutive P regs (k-rows base..base+7 of a 32-row half).
#define MKFRAG(dst, s, base)                                                  \
  {                                                                           \
    unsigned a0 = cvtpk_bf16(s[base + 0], s[base + 1]);                       \
    unsigned a1 = cvtpk_bf16(s[base + 2], s[base + 3]);                       \
    unsigned b0 = cvtpk_bf16(s[base + 4], s[base + 5]);                       \
    unsigned b1 = cvtpk_bf16(s[base + 6], s[base + 7]);                       \
    unsigned oa0 = shx32(a0), oa1 = shx32(a1), ob0 = shx32(b0), ob1 = shx32(b1); \
    dst = pack4(hi ? ob0 : a0, hi ? ob1 : a1, hi ? b0 : oa0, hi ? b1 : oa1);  \
  }

  STAGE(0, 0);
  asm volatile("s_waitcnt vmcnt(0)" ::: "memory");
  __syncthreads();

  for (int t = 0; t < NT; ++t) {
    const int bb = t & 1;
    if (t + 1 < NT) STAGE(t + 1, bb ^ 1);

    // ---- S^T = K Q^T : sa0 = k-rows 0..31, sa1 = k-rows 32..63 ----
    f32x16 sa0 = {}, sa1 = {};
#pragma unroll
    for (int ds = 0; ds < 4; ++ds) {
      const int ch = 2 * ds + hi;
      bf16x8 k0 = *(const bf16x8*)&Ks[bb][lq * 64 + ((ch ^ (lq & 7)) << 3)];
      bf16x8 k1 = *(const bf16x8*)&Ks[bb][(32 + lq) * 64 + ((ch ^ (lq & 7)) << 3)];
      sa0 = __builtin_amdgcn_mfma_f32_32x32x16_bf16(k0, qf[ds], sa0, 0, 0, 0);
      sa1 = __builtin_amdgcn_mfma_f32_32x32x16_bf16(k1, qf[ds], sa1, 0, 0, 0);
    }

    // ---- online softmax, fully in-register (q = lq; k split across lane pair) ----
    float tmx[16];
#pragma unroll
    for (int i = 0; i < 16; ++i) tmx[i] = fmaxf(sa0[i], sa1[i]);
#pragma unroll
    for (int st = 8; st > 0; st >>= 1)
#pragma unroll
      for (int i = 0; i < st; ++i) tmx[i] = fmaxf(tmx[i], tmx[i + st]);
    float pmax = tmx[0];
    pmax = fmaxf(pmax, __shfl_xor(pmax, 32, 64));

    // T13 defer-max: skip the O-rescale pass while max growth is bounded.
    if (!__all(pmax - m <= THR)) {
      float mnew = fmaxf(m, pmax);
      float rfac = exp2fast((m - mnew) * SCL);
      m = mnew;
      l *= rfac;
      if (hi == 0) rbc[wq][lq] = rfac;
      f32x4 rf[4];
#pragma unroll
      for (int g = 0; g < 4; ++g) rf[g] = *(const f32x4*)&rbc[wq][g * 8 + hi * 4];
#pragma unroll
      for (int i = 0; i < 16; ++i) {
        float r = rf[i >> 2][i & 3];
        oacc[0][i] *= r;
        oacc[1][i] *= r;
      }
    }
    float nmc = -m * SCL;

#pragma unroll
    for (int i = 0; i < 16; ++i) sa0[i] = exp2fast(fmaf(sa0[i], SCL, nmc));
#pragma unroll
    for (int i = 0; i < 16; ++i) sa1[i] = exp2fast(fmaf(sa1[i], SCL, nmc));

    float ts[16];
#pragma unroll
    for (int i = 0; i < 16; ++i) ts[i] = sa0[i] + sa1[i];
#pragma unroll
    for (int st = 8; st > 0; st >>= 1)
#pragma unroll
      for (int i = 0; i < st; ++i) ts[i] += ts[i + st];
    float psum = ts[0];
    psum += __shfl_xor(psum, 32, 64);
    l += psum;

    // ---- P -> bf16 A-fragments (cvt_pk + shfl_xor exchange; no LDS) ----
    bf16x8 pav[4];
    MKFRAG(pav[0], sa0, 0);
    MKFRAG(pav[1], sa0, 8);
    MKFRAG(pav[2], sa1, 0);
    MKFRAG(pav[3], sa1, 8);

    // ---- O += P V ----
#pragma unroll
    for (int ks = 0; ks < 4; ++ks) {
      const int ch = 2 * ks + hi;
      bf16x8 v0 = *(const bf16x8*)&Vs[bb][lq * 64 + ((ch ^ (lq & 7)) << 3)];
      bf16x8 v1 = *(const bf16x8*)&Vs[bb][(32 + lq) * 64 + ((ch ^ (lq & 7)) << 3)];
      oacc[0] = __builtin_amdgcn_mfma_f32_32x32x16_bf16(pav[ks], v0, oacc[0], 0, 0, 0);
      oacc[1] = __builtin_amdgcn_mfma_f32_32x32x16_bf16(pav[ks], v1, oacc[1], 0, 0, 0);
    }

    asm volatile("s_waitcnt vmcnt(0)" ::: "memory");
    __syncthreads();
  }
#undef STAGE
#undef MKFRAG

  // ---- epilogue: O = acc / l ----
  if (hi == 0) rbc[wq][lq] = 1.0f / l;
  f32x4 lf[4];
#pragma unroll
  for (int g = 0; g < 4; ++g) lf[g] = *(const f32x4*)&rbc[wq][g * 8 + hi * 4];
  unsigned short* ob = O + (size_t)(b * Seq + q0 + wq * 32) * E + h * 64 + lq;
#pragma unroll
  for (int db = 0; db < 2; ++db)
#pragma unroll
    for (int i = 0; i < 16; ++i) {
      int ql = (i & 3) + 8 * (i >> 2) + 4 * hi;
      ob[(size_t)ql * E + db * 32] = f2bf(oacc[db][i] * lf[i >> 2][i & 3]);
    }
}

// ---------------- launch ----------------
extern "C" void kernel_launch(void* const* d_in, const int* in_sizes, int n_in,
                              void* d_out, int out_size, void* d_ws, size_t ws_size,
                              hipStream_t stream) {
  const float* x = (const float*)d_in[0];
  const float* w_qkv = (const float*)d_in[1];
  const float* b_qkv = (const float*)d_in[2];
  const float* w_o = (const float*)d_in[3];
  const float* b_o = (const float*)d_in[4];
  float* out = (float*)d_out;
  char* ws = (char*)d_ws;

  unsigned short* xb  = (unsigned short*)(ws + 0);           // 16 MiB
  unsigned short* wqt = (unsigned short*)(ws + 16777216);    // 6 MiB
  unsigned short* wot = (unsigned short*)(ws + 23068672);    // 2 MiB
  unsigned short* qkb = (unsigned short*)(ws + 25165824);    // 32 MiB  [B*S][2E]
  unsigned short* vtb = (unsigned short*)(ws + 58720256);    // 16 MiB  [B*H][64][S]
  unsigned short* atO = (unsigned short*)(ws + 75497472);    // 16 MiB

  cast_f32_bf16<<<4096, 256, 0, stream>>>(x, xb);
  tcast<<<dim3(48, 16), 256, 0, stream>>>(w_qkv, wqt, DIN, N3);
  tcast<<<dim3(16, 16), 256, 0, stream>>>(w_o, wot, E, E);
  gemm_bt<0, 1><<<1536, 256, 0, stream>>>(xb, wqt, b_qkv, qkb, vtb, N3, DIN);
  attn<<<dim3(Seq / 128, Bn * H), 256, 0, stream>>>(qkb, vtb, atO);
  gemm_bt<1, 0><<<512, 256, 0, stream>>>(atO, wot, b_o, out, nullptr, E, E);
}

// Round 10
// 307.280 us; speedup vs baseline: 1.5700x; 1.0665x over previous
//
#include <hip/hip_runtime.h>

typedef __attribute__((ext_vector_type(8))) short bf16x8;
typedef __attribute__((ext_vector_type(4))) float f32x4;
typedef __attribute__((ext_vector_type(16))) float f32x16;
typedef __attribute__((ext_vector_type(4))) unsigned short u16x4;

#define DEV static __device__ __forceinline__

constexpr int Bn = 4, Seq = 2048, DIN = 1024, E = 1024, H = 16, HD = 64;
constexpr int Mrows = Bn * Seq;   // 8192
constexpr int N3 = 3 * E;         // 3072

DEV unsigned short f2bf(float f) {
  union { float f; unsigned u; } v; v.f = f;
  return (unsigned short)((v.u + 0x7FFFu + ((v.u >> 16) & 1u)) >> 16);
}

typedef const __attribute__((address_space(1))) unsigned int* gas_p;
typedef __attribute__((address_space(3))) unsigned int* las_p;

DEV void gload_lds16(const void* g, void* l) {
  __builtin_amdgcn_global_load_lds((gas_p)g, (las_p)l, 16, 0, 0);
}

DEV unsigned cvtpk_bf16(float lo, float hi) {
  unsigned r;
  asm("v_cvt_pk_bf16_f32 %0, %1, %2" : "=v"(r) : "v"(lo), "v"(hi));
  return r;
}
DEV float exp2fast(float x) {
  float r;
  asm("v_exp_f32 %0, %1" : "=v"(r) : "v"(x));
  return r;
}
DEV unsigned shx32(unsigned v) { return (unsigned)__shfl_xor((int)v, 32, 64); }
DEV bf16x8 pack4(unsigned w0, unsigned w1, unsigned w2, unsigned w3) {
  union { unsigned u[4]; bf16x8 b; } cv;
  cv.u[0] = w0; cv.u[1] = w1; cv.u[2] = w2; cv.u[3] = w3;
  return cv.b;
}

// ---------------- cast x (fp32 -> bf16, same layout) ----------------
__global__ void cast_f32_bf16(const float* __restrict__ in,
                              unsigned short* __restrict__ out) {
  size_t i = ((size_t)blockIdx.x * 256 + threadIdx.x) * 8;
  float4 a = *(const float4*)(in + i);
  float4 b = *(const float4*)(in + i + 4);
  union { unsigned short us[8]; bf16x8 v; } r;
  r.us[0] = f2bf(a.x); r.us[1] = f2bf(a.y); r.us[2] = f2bf(a.z); r.us[3] = f2bf(a.w);
  r.us[4] = f2bf(b.x); r.us[5] = f2bf(b.y); r.us[6] = f2bf(b.z); r.us[7] = f2bf(b.w);
  *(bf16x8*)(out + i) = r.v;
}

// ------------- transpose+cast weights: in [K][N] f32 -> out [N][K] bf16 -------------
__global__ void tcast(const float* __restrict__ in, unsigned short* __restrict__ out,
                      int K, int N) {
  __shared__ float tile[64][65];
  int n0 = blockIdx.x * 64, k0 = blockIdx.y * 64;
  int tx = threadIdx.x & 63, ty = threadIdx.x >> 6;
#pragma unroll
  for (int i = 0; i < 64; i += 4)
    tile[ty + i][tx] = in[(size_t)(k0 + ty + i) * N + n0 + tx];
  __syncthreads();
#pragma unroll
  for (int i = 0; i < 64; i += 4)
    out[(size_t)(n0 + ty + i) * K + k0 + tx] = f2bf(tile[tx][ty + i]);
}

// ------- GEMM, 256-row tile, 512 threads, BK=64, 2-phase pipelined dbuf LDS -------
// C[M][N] = A[M][K] * Bt[N][K]^T + bias.  BM=256 fixed; BN template (192 or 128).
// 8 waves as 2(M) x 4(N); per-wave output 128 x BN/4.
// LDS tiles 16B-chunk XOR swizzled (chunk c at row r holds global chunk c^(r&7)),
// staged via pre-swizzled global source + linear gload_lds dest (rule #21).
// EPI 0: bf16 out. EPI 1: f32 out. VOUT 1: split epilogue (q,k->[M][2E], v->V^T).
template <int BN, int EPI, int VOUT>
__global__ __launch_bounds__(512, 2) void gemm256(
    const unsigned short* __restrict__ A, const unsigned short* __restrict__ Bt,
    const float* __restrict__ bias, void* __restrict__ Cout,
    unsigned short* __restrict__ vt, int N, int K) {
  constexpr int BM = 256, BK = 64;
  constexpr int NSPAN = BN / 4;      // per-wave N span
  constexpr int NF = NSPAN / 16;     // N frags per wave (3 or 2)
  constexpr int AC = BM * BK / 8;    // 2048 16B-chunks in A tile
  constexpr int BC = BN * BK / 8;    // 1536 / 1024
  __shared__ alignas(16) unsigned short As[2][BM * BK];
  __shared__ alignas(16) unsigned short Bs[2][BN * BK];

  const int tid = threadIdx.x;
  const int wave = tid >> 6, lane = tid & 63;
  const int wr = wave >> 2, wc = wave & 3;
  const int llo = lane & 15, lhi = lane >> 4;
  const int bm = blockIdx.x * BM, bn = blockIdx.y * BN;

  f32x4 acc[8][NF] = {};

#define GSTAGE(kt, bufi)                                                      \
  {                                                                           \
    _Pragma("unroll") for (int i = 0; i < AC / 512; ++i) {                    \
      int c = i * 512 + tid;                                                  \
      int row = c >> 3, cs = c & 7;                                           \
      int col = ((cs ^ (row & 7)) << 3);                                      \
      gload_lds16(A + (size_t)(bm + row) * K + (kt) + col,                    \
                  (char*)&As[bufi][0] + c * 16);                              \
    }                                                                         \
    _Pragma("unroll") for (int i = 0; i < BC / 512; ++i) {                    \
      int c = i * 512 + tid;                                                  \
      int row = c >> 3, cs = c & 7;                                           \
      int col = ((cs ^ (row & 7)) << 3);                                      \
      gload_lds16(Bt + (size_t)(bn + row) * K + (kt) + col,                   \
                  (char*)&Bs[bufi][0] + c * 16);                              \
    }                                                                         \
  }

  const int NT = K / BK;  // 16
  GSTAGE(0, 0);
  asm volatile("s_waitcnt vmcnt(0)" ::: "memory");
  __syncthreads();

  for (int t = 0; t < NT; ++t) {
    const int buf = t & 1;
    if (t + 1 < NT) GSTAGE((t + 1) * BK, buf ^ 1);

#pragma unroll
    for (int kh = 0; kh < 2; ++kh) {
      bf16x8 af[8], bfv[NF];
#pragma unroll
      for (int mt = 0; mt < 8; ++mt) {
        int row = wr * 128 + mt * 16 + llo;
        af[mt] = *(const bf16x8*)&As[buf][row * 64 + (((kh * 4 + lhi) ^ (row & 7)) << 3)];
      }
#pragma unroll
      for (int nt = 0; nt < NF; ++nt) {
        int row = wc * NSPAN + nt * 16 + llo;
        bfv[nt] = *(const bf16x8*)&Bs[buf][row * 64 + (((kh * 4 + lhi) ^ (row & 7)) << 3)];
      }
#pragma unroll
      for (int mt = 0; mt < 8; ++mt)
#pragma unroll
        for (int nt = 0; nt < NF; ++nt)
          acc[mt][nt] =
              __builtin_amdgcn_mfma_f32_16x16x32_bf16(af[mt], bfv[nt], acc[mt][nt], 0, 0, 0);
    }

    if (t + 1 < NT) {
      asm volatile("s_waitcnt vmcnt(0)" ::: "memory");
      __syncthreads();
    }
  }
#undef GSTAGE

  // ---- epilogue ----
#pragma unroll
  for (int nt = 0; nt < NF; ++nt) {
    int n = bn + wc * NSPAN + nt * 16 + llo;
    float bv = bias[n];
    if constexpr (VOUT == 1) {
      int h = n / 192, inner = n % 192;  // wave-uniform per nt (16-spans don't straddle 128)
      if (inner < 128) {
        int col = h * 128 + inner;
#pragma unroll
        for (int mt = 0; mt < 8; ++mt)
#pragma unroll
          for (int r = 0; r < 4; ++r) {
            int m = bm + wr * 128 + mt * 16 + lhi * 4 + r;
            ((unsigned short*)Cout)[(size_t)m * 2048 + col] = f2bf(acc[mt][nt][r] + bv);
          }
      } else {
        int d = inner - 128;
#pragma unroll
        for (int mt = 0; mt < 8; ++mt) {
          int m = bm + wr * 128 + mt * 16 + lhi * 4;
          int b = m >> 11, s = m & 2047;
          u16x4 pk;
#pragma unroll
          for (int r = 0; r < 4; ++r) pk[r] = f2bf(acc[mt][nt][r] + bv);
          *(u16x4*)&vt[(size_t)((b * 16 + h) * 64 + d) * Seq + s] = pk;
        }
      }
    } else {
#pragma unroll
      for (int mt = 0; mt < 8; ++mt) {
#pragma unroll
        for (int r = 0; r < 4; ++r) {
          int m = bm + wr * 128 + mt * 16 + lhi * 4 + r;
          float v = acc[mt][nt][r] + bv;
          if constexpr (EPI == 0)
            ((unsigned short*)Cout)[(size_t)m * N + n] = f2bf(v);
          else
            ((float*)Cout)[(size_t)m * N + n] = v;
        }
      }
    }
  }
}

// ---------------- flash attention (swapped-QK^T, 32x32 MFMA, in-register softmax) ----
// qk: [B*S][2E] bf16, per (b,s): h*128 + {0:q, 64:k}
// vt: [B*H][64][Seq] bf16 (V^T per head)
// O:  [B*S][E]  bf16
// Half-exchange via __shfl_xor(.,32) (direction-proof).
__global__ __launch_bounds__(256) void attn(const unsigned short* __restrict__ qk,
                                            const unsigned short* __restrict__ vt,
                                            unsigned short* __restrict__ O) {
  constexpr int KB = 64, NT = Seq / KB;
  constexpr float SCL = 0.18033688011112042f;  // 0.125 * log2(e)
  __shared__ alignas(16) unsigned short Ks[2][64 * 64];  // [k][d], 16B-chunk XOR swizzled
  __shared__ alignas(16) unsigned short Vs[2][64 * 64];  // [d][k], same swizzle
  __shared__ float rbc[4][32];                           // per-wave broadcast line

  const int bh = blockIdx.y, b = bh >> 4, h = bh & 15;
  const int q0 = blockIdx.x * 128;
  const int tid = threadIdx.x, wq = tid >> 6, lane = tid & 63;
  const int lq = lane & 31, hi = lane >> 5;

  const unsigned short* qbase = qk + (size_t)(b * Seq) * 2048 + h * 128;
  const unsigned short* kbase = qbase + 64;
  const unsigned short* vtb = vt + (size_t)bh * 64 * Seq;

  // Q B-fragments: lane holds q-row lq, d = ds*16 + hi*8 + 0..7
  bf16x8 qf[4];
  {
    const unsigned short* qrow = qbase + (size_t)(q0 + wq * 32 + lq) * 2048 + hi * 8;
#pragma unroll
    for (int ds = 0; ds < 4; ++ds) qf[ds] = *(const bf16x8*)(qrow + ds * 16);
  }

  float m = -1e30f, l = 0.f;
  f32x16 oacc[2] = {};

  const int srow = lane >> 3;
  const int scol = ((lane & 7) ^ srow) * 8;  // pre-swizzled source chunk

#define STAGE(t, bb)                                                         \
  {                                                                          \
    int kv0 = (t) * KB;                                                      \
    _Pragma("unroll") for (int i = 0; i < 2; ++i) {                          \
      int chunk = i * 4 + wq;                                                \
      int row = chunk * 8 + srow;                                            \
      gload_lds16(kbase + (size_t)(kv0 + row) * 2048 + scol,                 \
                  (char*)&Ks[bb][0] + chunk * 1024);                         \
      gload_lds16(vtb + (size_t)row * Seq + kv0 + scol,                      \
                  (char*)&Vs[bb][0] + chunk * 1024);                         \
    }                                                                        \
  }

// Build A-fragment words from 8 consecutive P regs (k-rows base..base+7 of a 32-row half).
#define MKFRAG(dst, s, base)                                                  \
  {                                                                           \
    unsigned a0 = cvtpk_bf16(s[base + 0], s[base + 1]);                       \
    unsigned a1 = cvtpk_bf16(s[base + 2], s[base + 3]);                       \
    unsigned b0 = cvtpk_bf16(s[base + 4], s[base + 5]);                       \
    unsigned b1 = cvtpk_bf16(s[base + 6], s[base + 7]);                       \
    unsigned oa0 = shx32(a0), oa1 = shx32(a1), ob0 = shx32(b0), ob1 = shx32(b1); \
    dst = pack4(hi ? ob0 : a0, hi ? ob1 : a1, hi ? b0 : oa0, hi ? b1 : oa1);  \
  }

  STAGE(0, 0);
  asm volatile("s_waitcnt vmcnt(0)" ::: "memory");
  __syncthreads();

  for (int t = 0; t < NT; ++t) {
    const int bb = t & 1;
    if (t + 1 < NT) STAGE(t + 1, bb ^ 1);

    // ---- S^T = K Q^T : sa0 = k-rows 0..31, sa1 = k-rows 32..63 ----
    f32x16 sa0 = {}, sa1 = {};
#pragma unroll
    for (int ds = 0; ds < 4; ++ds) {
      const int ch = 2 * ds + hi;
      bf16x8 k0 = *(const bf16x8*)&Ks[bb][lq * 64 + ((ch ^ (lq & 7)) << 3)];
      bf16x8 k1 = *(const bf16x8*)&Ks[bb][(32 + lq) * 64 + ((ch ^ (lq & 7)) << 3)];
      sa0 = __builtin_amdgcn_mfma_f32_32x32x16_bf16(k0, qf[ds], sa0, 0, 0, 0);
      sa1 = __builtin_amdgcn_mfma_f32_32x32x16_bf16(k1, qf[ds], sa1, 0, 0, 0);
    }

    // ---- online softmax, fully in-register (q = lq; k split across lane pair) ----
    float tmx[16];
#pragma unroll
    for (int i = 0; i < 16; ++i) tmx[i] = fmaxf(sa0[i], sa1[i]);
#pragma unroll
    for (int st = 8; st > 0; st >>= 1)
#pragma unroll
      for (int i = 0; i < st; ++i) tmx[i] = fmaxf(tmx[i], tmx[i + st]);
    float pmax = tmx[0];
    pmax = fmaxf(pmax, __shfl_xor(pmax, 32, 64));

    float mnew = fmaxf(m, pmax);
    float rfac = exp2fast((m - mnew) * SCL);
    m = mnew;
    float nmc = -m * SCL;

#pragma unroll
    for (int i = 0; i < 16; ++i) sa0[i] = exp2fast(fmaf(sa0[i], SCL, nmc));
#pragma unroll
    for (int i = 0; i < 16; ++i) sa1[i] = exp2fast(fmaf(sa1[i], SCL, nmc));

    float ts[16];
#pragma unroll
    for (int i = 0; i < 16; ++i) ts[i] = sa0[i] + sa1[i];
#pragma unroll
    for (int st = 8; st > 0; st >>= 1)
#pragma unroll
      for (int i = 0; i < st; ++i) ts[i] += ts[i + st];
    float psum = ts[0];
    psum += __shfl_xor(psum, 32, 64);
    l = l * rfac + psum;

    // ---- P -> bf16 A-fragments (cvt_pk + shfl_xor exchange; no LDS) ----
    bf16x8 pav[4];
    MKFRAG(pav[0], sa0, 0);
    MKFRAG(pav[1], sa0, 8);
    MKFRAG(pav[2], sa1, 0);
    MKFRAG(pav[3], sa1, 8);

    // ---- per-q rescale of O (q lives in reg dim: q = (i&3)+8*(i>>2)+4*hi) ----
    if (hi == 0) rbc[wq][lq] = rfac;
    f32x4 rf[4];
#pragma unroll
    for (int g = 0; g < 4; ++g) rf[g] = *(const f32x4*)&rbc[wq][g * 8 + hi * 4];
#pragma unroll
    for (int i = 0; i < 16; ++i) {
      float r = rf[i >> 2][i & 3];
      oacc[0][i] *= r;
      oacc[1][i] *= r;
    }

    // ---- O += P V ----
#pragma unroll
    for (int ks = 0; ks < 4; ++ks) {
      const int ch = 2 * ks + hi;
      bf16x8 v0 = *(const bf16x8*)&Vs[bb][lq * 64 + ((ch ^ (lq & 7)) << 3)];
      bf16x8 v1 = *(const bf16x8*)&Vs[bb][(32 + lq) * 64 + ((ch ^ (lq & 7)) << 3)];
      oacc[0] = __builtin_amdgcn_mfma_f32_32x32x16_bf16(pav[ks], v0, oacc[0], 0, 0, 0);
      oacc[1] = __builtin_amdgcn_mfma_f32_32x32x16_bf16(pav[ks], v1, oacc[1], 0, 0, 0);
    }

    asm volatile("s_waitcnt vmcnt(0)" ::: "memory");
    __syncthreads();
  }
#undef STAGE
#undef MKFRAG

  // ---- epilogue: O = acc / l ----
  if (hi == 0) rbc[wq][lq] = 1.0f / l;
  f32x4 lf[4];
#pragma unroll
  for (int g = 0; g < 4; ++g) lf[g] = *(const f32x4*)&rbc[wq][g * 8 + hi * 4];
  unsigned short* ob = O + (size_t)(b * Seq + q0 + wq * 32) * E + h * 64 + lq;
#pragma unroll
  for (int db = 0; db < 2; ++db)
#pragma unroll
    for (int i = 0; i < 16; ++i) {
      int ql = (i & 3) + 8 * (i >> 2) + 4 * hi;
      ob[(size_t)ql * E + db * 32] = f2bf(oacc[db][i] * lf[i >> 2][i & 3]);
    }
}

// ---------------- launch ----------------
extern "C" void kernel_launch(void* const* d_in, const int* in_sizes, int n_in,
                              void* d_out, int out_size, void* d_ws, size_t ws_size,
                              hipStream_t stream) {
  const float* x = (const float*)d_in[0];
  const float* w_qkv = (const float*)d_in[1];
  const float* b_qkv = (const float*)d_in[2];
  const float* w_o = (const float*)d_in[3];
  const float* b_o = (const float*)d_in[4];
  float* out = (float*)d_out;
  char* ws = (char*)d_ws;

  unsigned short* xb  = (unsigned short*)(ws + 0);           // 16 MiB
  unsigned short* wqt = (unsigned short*)(ws + 16777216);    // 6 MiB
  unsigned short* wot = (unsigned short*)(ws + 23068672);    // 2 MiB
  unsigned short* qkb = (unsigned short*)(ws + 25165824);    // 32 MiB  [B*S][2E]
  unsigned short* vtb = (unsigned short*)(ws + 58720256);    // 16 MiB  [B*H][64][S]
  unsigned short* atO = (unsigned short*)(ws + 75497472);    // 16 MiB

  cast_f32_bf16<<<4096, 256, 0, stream>>>(x, xb);
  tcast<<<dim3(48, 16), 256, 0, stream>>>(w_qkv, wqt, DIN, N3);
  tcast<<<dim3(16, 16), 256, 0, stream>>>(w_o, wot, E, E);
  gemm256<192, 0, 1><<<dim3(Mrows / 256, N3 / 192), 512, 0, stream>>>(
      xb, wqt, b_qkv, qkb, vtb, N3, DIN);
  attn<<<dim3(Seq / 128, Bn * H), 256, 0, stream>>>(qkb, vtb, atO);
  gemm256<128, 1, 0><<<dim3(Mrows / 256, E / 128), 512, 0, stream>>>(
      atO, wot, b_o, out, nullptr, E, E);
}